// Round 4
// baseline (225.553 us; speedup 1.0000x reference)
//
#include <hip/hip_runtime.h>
#include <math.h>

#define HW 48
#define NPIX 2304          // 48*48
#define CF 64
#define CQ 32
#define RAD 12
#define PP 25
#define NTAP 625           // 25*25
#define KTOP 20
#define DILINT 16
#define QW 192
#define PAD 64
#define PDIM 176           // HW + 2*PAD
#define CWW 28             // padded tap-row width (25 -> 28, multiple of 4)

// ---- helpers ---------------------------------------------------------------

// ref_index may arrive as int32 or int64; detect via first 8 bytes.
__device__ inline int read_ref_index(const void* rip, int r) {
    const long long* p64 = (const long long*)rip;
    long long v0 = p64[0];
    if (v0 >= 0 && v0 < 1000000) return (int)p64[r];   // plausible int64 layout
    return ((const int*)rip)[r];                       // int32 layout
}

// ---- kernel 1: layout prep -------------------------------------------------
// ftT[p][c], qrT[r][p][c] always; frMap is either the zero-padded map
// frP[r][176][176][64] (padded=1) or the compact frT[r][p][c] (padded=0).
__global__ void prep_kernel(const float* __restrict__ fr,
                            const float* __restrict__ ft,
                            const float* __restrict__ q, int nref,
                            float* __restrict__ ftT,
                            float* __restrict__ qrT,
                            float* __restrict__ frMap, int padded) {
    int i = blockIdx.x * blockDim.x + threadIdx.x;
    int tft = NPIX * CF;
    int tqr = nref * NPIX * CQ;
    if (i < tft) {
        int p = i >> 6, c = i & 63;
        ftT[i] = ft[c * NPIX + p];
        return;
    }
    i -= tft;
    if (i < tqr) {
        int rr = i / (NPIX * CQ);
        int rem = i % (NPIX * CQ);
        int p = rem >> 5, c = rem & 31;
        int y = p / HW, x = p % HW;
        qrT[i] = q[(((size_t)rr * CQ + c) * QW + 4 * y) * QW + 4 * x];
        return;
    }
    i -= tqr;
    if (padded) {
        int tmap = nref * PDIM * PDIM * CF;
        if (i < tmap) {
            int c = i & 63;
            int j = i >> 6;
            int xx = j % PDIM; j /= PDIM;
            int yy = j % PDIM;
            int rr = j / PDIM;
            int y = yy - PAD, x = xx - PAD;
            float v = 0.f;
            if (y >= 0 && y < HW && x >= 0 && x < HW)
                v = fr[((size_t)rr * CF + c) * NPIX + y * HW + x];
            frMap[i] = v;
        }
    } else {
        int tfr = nref * NPIX * CF;
        if (i < tfr) {
            int rr = i / (NPIX * CF);
            int rem = i % (NPIX * CF);
            int p = rem >> 6, c = rem & 63;
            frMap[i] = fr[((size_t)rr * CF + c) * NPIX + p];
        }
    }
}

// ---- kernel 2 (padded): wave-per-(pixel,ref), no bounds checks, no div/mod -
__global__ __launch_bounds__(256) void corr_topk_pad(
    const float* __restrict__ ftT, const float* __restrict__ frP,
    const void* __restrict__ refIdx, const void* __restrict__ curInd,
    float* __restrict__ offY, float* __restrict__ offX,
    float* __restrict__ vals, int* __restrict__ topi) {
    __shared__ float cw[4][PP * CWW];     // 700 per wave
    __shared__ float dg[4][26 * CWW];     // 728 per wave

    int tid = threadIdx.x;
    int wid = tid >> 6, lane = tid & 63;
    int g = lane >> 4;          // tap slot within round (0..3)
    int cs = lane & 15;         // 4-channel slice
    int p = blockIdx.x * 4 + wid;
    int r = blockIdx.y;
    int y = p / HW, x = p % HW;

    int cur = ((const int*)curInd)[0];
    int gap = cur - read_ref_index(refIdx, r);
    bool isLong = gap > DILINT;
    int dil = isLong ? min(4, gap / DILINT + 1) : 1;

    float4 fq = ((const float4*)(ftT + (size_t)p * CF))[cs];
    const float* mapr = frP + (size_t)r * PDIM * PDIM * CF;
    float* cwp = cw[wid];

    // ---- integer-tap pass: 25 rows x 7 rounds x 4 taps (28 dx slots) -------
    {
        int row0 = y + PAD - RAD * dil;
        int col0 = x + PAD - RAD * dil + g * dil;
        const float* base = mapr + ((size_t)row0 * PDIM + col0) * CF + cs * 4;
        int rowstep = dil * PDIM * CF;
        int colstep = 4 * dil * CF;
        for (int dy = 0; dy < PP; ++dy) {
            const float* rp = base + dy * rowstep;
            int ws0 = dy * CWW + g;
#pragma unroll
            for (int i = 0; i < 7; ++i) {
                float4 b = *(const float4*)(rp + i * colstep);
                float s = fq.x * b.x + fq.y * b.y + fq.z * b.z + fq.w * b.w;
                s += __shfl_xor(s, 1, 64);
                s += __shfl_xor(s, 2, 64);
                s += __shfl_xor(s, 4, 64);
                s += __shfl_xor(s, 8, 64);
                if (cs == 0) cwp[ws0 + 4 * i] = s;
            }
        }
    }
    __builtin_amdgcn_wave_barrier();
    asm volatile("s_waitcnt lgkmcnt(0)" ::: "memory");
    __builtin_amdgcn_sched_barrier(0);

    // pull valid taps into registers (t = dy*25+dx, reference index order)
    float creg[10];
#pragma unroll
    for (int j = 0; j < 10; ++j) {
        int t = lane + 64 * j;
        creg[j] = (t < NTAP) ? cwp[(t / PP) * CWW + t % PP] : -INFINITY;
    }

    if (isLong) {
        // softmax over 625 taps -> expected offsets (shuffle reduce)
        float M = -INFINITY;
#pragma unroll
        for (int j = 0; j < 10; ++j) M = fmaxf(M, creg[j]);
#pragma unroll
        for (int s = 32; s; s >>= 1) M = fmaxf(M, __shfl_xor(M, s, 64));
        float s0 = 0.f, sy = 0.f, sx = 0.f;
#pragma unroll
        for (int j = 0; j < 10; ++j) {
            int t = lane + 64 * j;
            if (t < NTAP) {
                float e = expf(creg[j] - M);
                int dy = t / PP - RAD, dx = t % PP - RAD;
                s0 += e; sy += e * (float)dy; sx += e * (float)dx;
            }
        }
#pragma unroll
        for (int s = 32; s; s >>= 1) {
            s0 += __shfl_xor(s0, s, 64);
            sy += __shfl_xor(sy, s, 64);
            sx += __shfl_xor(sx, s, 64);
        }
        float oy = sy / s0 * (float)dil;
        float ox = sx / s0 * (float)dil;
        if (lane == 0) { offY[r * NPIX + p] = oy; offX[r * NPIX + p] = ox; }

        // 26x28 corner-dot grid (pad=64 covers iy0/ix0 +/- excursions)
        float fy = (float)y + oy, fx = (float)x + ox;
        float fy0 = floorf(fy), fx0 = floorf(fx);
        float wy = fy - fy0, wx = fx - fx0;
        int iy0 = (int)fy0, ix0 = (int)fx0;
        float* dgw = dg[wid];
        {
            int row0 = iy0 + PAD - RAD;
            int col0 = ix0 + PAD - RAD + g;
            const float* base = mapr + ((size_t)row0 * PDIM + col0) * CF + cs * 4;
            int colstep = 4 * CF;
            for (int a = 0; a < 26; ++a) {
                const float* rp = base + a * PDIM * CF;
                int ws0 = a * CWW + g;
#pragma unroll
                for (int i = 0; i < 7; ++i) {
                    float4 b = *(const float4*)(rp + i * colstep);
                    float s = fq.x * b.x + fq.y * b.y + fq.z * b.z + fq.w * b.w;
                    s += __shfl_xor(s, 1, 64);
                    s += __shfl_xor(s, 2, 64);
                    s += __shfl_xor(s, 4, 64);
                    s += __shfl_xor(s, 8, 64);
                    if (cs == 0) dgw[ws0 + 4 * i] = s;
                }
            }
        }
        __builtin_amdgcn_wave_barrier();
        asm volatile("s_waitcnt lgkmcnt(0)" ::: "memory");
        __builtin_amdgcn_sched_barrier(0);

        float w00 = (1.f - wy) * (1.f - wx), w01 = (1.f - wy) * wx;
        float w10 = wy * (1.f - wx), w11 = wy * wx;
#pragma unroll
        for (int j = 0; j < 10; ++j) {
            int t = lane + 64 * j;
            if (t < NTAP) {
                int a = t / PP, bcol = t % PP;
                creg[j] = w00 * dgw[a * CWW + bcol] + w01 * dgw[a * CWW + bcol + 1] +
                          w10 * dgw[(a + 1) * CWW + bcol] + w11 * dgw[(a + 1) * CWW + bcol + 1];
            }
        }
    }

    // top-K: 20 rounds of register argmax + shuffle butterfly; tie -> lowest t
    float* vout = vals + (size_t)r * KTOP * NPIX + p;
    int* iout = topi + (size_t)r * KTOP * NPIX + p;
    for (int k = 0; k < KTOP; ++k) {
        float bv = creg[0]; int bt = lane;
#pragma unroll
        for (int j = 1; j < 10; ++j) {
            int t = lane + 64 * j;
            if (creg[j] > bv) { bv = creg[j]; bt = t; }
        }
#pragma unroll
        for (int s = 32; s; s >>= 1) {
            float ov = __shfl_xor(bv, s, 64);
            int ot = __shfl_xor(bt, s, 64);
            if (ov > bv || (ov == bv && ot < bt)) { bv = ov; bt = ot; }
        }
        if (lane == 0) { vout[(size_t)k * NPIX] = bv; iout[(size_t)k * NPIX] = bt; }
        if ((bt & 63) == lane) {
            int jj = bt >> 6;
#pragma unroll
            for (int j = 0; j < 10; ++j)
                if (j == jj) creg[j] = -INFINITY;
        }
    }
}

// ---- kernel 2 (fallback, unpadded): the proven round-3 kernel --------------
__global__ __launch_bounds__(256) void corr_topk_fb(
    const float* __restrict__ ftT, const float* __restrict__ frT,
    const void* __restrict__ refIdx, const void* __restrict__ curInd,
    float* __restrict__ offY, float* __restrict__ offX,
    float* __restrict__ vals, int* __restrict__ topi) {
    __shared__ float corrLds[4][640];
    __shared__ float dg[4][680];

    int tid = threadIdx.x;
    int wid = tid >> 6, lane = tid & 63;
    int g = lane >> 4;
    int cs = lane & 15;
    int p = blockIdx.x * 4 + wid;
    int r = blockIdx.y;
    int y = p / HW, x = p % HW;

    int cur = ((const int*)curInd)[0];
    int gap = cur - read_ref_index(refIdx, r);
    bool isLong = gap > DILINT;
    int dil = isLong ? min(4, gap / DILINT + 1) : 1;

    float4 fq = ((const float4*)(ftT + (size_t)p * CF))[cs];
    const float* frb = frT + (size_t)r * NPIX * CF;
    float* cwp = corrLds[wid];

    for (int rr = 0; rr < 157; ++rr) {
        int t = 4 * rr + g;
        float s = 0.f;
        bool valid = t < NTAP;
        if (valid) {
            int dy = t / PP - RAD, dx = t % PP - RAD;
            int yy = y + dy * dil, xx = x + dx * dil;
            if (yy >= 0 && yy < HW && xx >= 0 && xx < HW) {
                float4 b = ((const float4*)(frb + (size_t)(yy * HW + xx) * CF))[cs];
                s = fq.x * b.x + fq.y * b.y + fq.z * b.z + fq.w * b.w;
            }
        }
        s += __shfl_xor(s, 1, 64);
        s += __shfl_xor(s, 2, 64);
        s += __shfl_xor(s, 4, 64);
        s += __shfl_xor(s, 8, 64);
        if (cs == 0 && valid) cwp[t] = s;
    }
    __builtin_amdgcn_wave_barrier();
    asm volatile("s_waitcnt lgkmcnt(0)" ::: "memory");
    __builtin_amdgcn_sched_barrier(0);

    if (isLong) {
        float M = -INFINITY;
#pragma unroll
        for (int j = 0; j < 10; ++j) {
            int t = lane + 64 * j;
            float v = (t < NTAP) ? cwp[t] : -INFINITY;
            M = fmaxf(M, v);
        }
#pragma unroll
        for (int s = 32; s; s >>= 1) M = fmaxf(M, __shfl_xor(M, s, 64));
        float s0 = 0.f, sy = 0.f, sx = 0.f;
#pragma unroll
        for (int j = 0; j < 10; ++j) {
            int t = lane + 64 * j;
            if (t < NTAP) {
                float e = expf(cwp[t] - M);
                int dy = t / PP - RAD, dx = t % PP - RAD;
                s0 += e; sy += e * (float)dy; sx += e * (float)dx;
            }
        }
#pragma unroll
        for (int s = 32; s; s >>= 1) {
            s0 += __shfl_xor(s0, s, 64);
            sy += __shfl_xor(sy, s, 64);
            sx += __shfl_xor(sx, s, 64);
        }
        float oy = sy / s0 * (float)dil;
        float ox = sx / s0 * (float)dil;
        if (lane == 0) { offY[r * NPIX + p] = oy; offX[r * NPIX + p] = ox; }

        float fy = (float)y + oy, fx = (float)x + ox;
        float fy0 = floorf(fy), fx0 = floorf(fx);
        float wy = fy - fy0, wx = fx - fx0;
        int iy0 = (int)fy0, ix0 = (int)fx0;
        float* dgw = dg[wid];
        for (int rr = 0; rr < 169; ++rr) {
            int idx = 4 * rr + g;
            int a = idx / 26, bcol = idx % 26;
            int yy = iy0 - RAD + a, xx = ix0 - RAD + bcol;
            float s = 0.f;
            if (yy >= 0 && yy < HW && xx >= 0 && xx < HW) {
                float4 b = ((const float4*)(frb + (size_t)(yy * HW + xx) * CF))[cs];
                s = fq.x * b.x + fq.y * b.y + fq.z * b.z + fq.w * b.w;
            }
            s += __shfl_xor(s, 1, 64);
            s += __shfl_xor(s, 2, 64);
            s += __shfl_xor(s, 4, 64);
            s += __shfl_xor(s, 8, 64);
            if (cs == 0) dgw[idx] = s;
        }
        __builtin_amdgcn_wave_barrier();
        asm volatile("s_waitcnt lgkmcnt(0)" ::: "memory");
        __builtin_amdgcn_sched_barrier(0);

        float w00 = (1.f - wy) * (1.f - wx), w01 = (1.f - wy) * wx;
        float w10 = wy * (1.f - wx), w11 = wy * wx;
#pragma unroll
        for (int j = 0; j < 10; ++j) {
            int t = lane + 64 * j;
            if (t < NTAP) {
                int a = t / PP, bcol = t % PP;
                cwp[t] = w00 * dgw[a * 26 + bcol] + w01 * dgw[a * 26 + bcol + 1] +
                         w10 * dgw[(a + 1) * 26 + bcol] + w11 * dgw[(a + 1) * 26 + bcol + 1];
            }
        }
        __builtin_amdgcn_wave_barrier();
        asm volatile("s_waitcnt lgkmcnt(0)" ::: "memory");
        __builtin_amdgcn_sched_barrier(0);
    }

    float creg[10];
#pragma unroll
    for (int j = 0; j < 10; ++j) {
        int t = lane + 64 * j;
        creg[j] = (t < NTAP) ? cwp[t] : -INFINITY;
    }

    float* vout = vals + (size_t)r * KTOP * NPIX + p;
    int* iout = topi + (size_t)r * KTOP * NPIX + p;
    for (int k = 0; k < KTOP; ++k) {
        float bv = creg[0]; int bt = lane;
#pragma unroll
        for (int j = 1; j < 10; ++j) {
            int t = lane + 64 * j;
            if (creg[j] > bv) { bv = creg[j]; bt = t; }
        }
#pragma unroll
        for (int s = 32; s; s >>= 1) {
            float ov = __shfl_xor(bv, s, 64);
            int ot = __shfl_xor(bt, s, 64);
            if (ov > bv || (ov == bv && ot < bt)) { bv = ov; bt = ot; }
        }
        if (lane == 0) { vout[(size_t)k * NPIX] = bv; iout[(size_t)k * NPIX] = bt; }
        if ((bt & 63) == lane) {
            int jj = bt >> 6;
#pragma unroll
            for (int j = 0; j < 10; ++j)
                if (j == jj) creg[j] = -INFINITY;
        }
    }
}

// ---- kernel 3: softmax over 60 vals + gather colors + blend ---------------
__global__ __launch_bounds__(256) void finalize_kernel(
    const float* __restrict__ qrT, const float* __restrict__ vals,
    const int* __restrict__ topi, const float* __restrict__ offY,
    const float* __restrict__ offX, const void* __restrict__ refIdx,
    const void* __restrict__ curInd, int nref, float* __restrict__ out) {
    int tid = threadIdx.x;
    int p = blockIdx.x * 8 + (tid >> 5);
    int c = tid & 31;
    if (p >= NPIX) return;
    int y = p / HW, x = p % HW;
    int cur = ((const int*)curInd)[0];
    int nk = nref * KTOP;

    float m = -INFINITY;
    for (int k = 0; k < nk; ++k) m = fmaxf(m, vals[(size_t)k * NPIX + p]);

    float ssum = 0.f, acc = 0.f;
    for (int rr = 0; rr < nref; ++rr) {
        int gap = cur - read_ref_index(refIdx, rr);
        bool isLong = gap > DILINT;
        float oy = 0.f, ox = 0.f;
        if (isLong) { oy = offY[rr * NPIX + p]; ox = offX[rr * NPIX + p]; }
        const float* qb = qrT + (size_t)rr * NPIX * CQ;
        for (int k = 0; k < KTOP; ++k) {
            int kk = rr * KTOP + k;
            float e = expf(vals[(size_t)kk * NPIX + p] - m);
            ssum += e;
            int id = topi[(size_t)kk * NPIX + p];
            int dr = id / PP - RAD, dc = id % PP - RAD;
            float img = 0.f;
            if (isLong) {
                float py = (float)y + oy + (float)dr;
                float px = (float)x + ox + (float)dc;
                float fy0 = floorf(py), fx0 = floorf(px);
                int y0 = (int)fy0, x0 = (int)fx0;
                float wy = py - fy0, wx = px - fx0;
                float w00 = (1.f - wy) * (1.f - wx), w01 = (1.f - wy) * wx;
                float w10 = wy * (1.f - wx), w11 = wy * wx;
                if (y0 >= 0 && y0 < HW && x0 >= 0 && x0 < HW)
                    img += w00 * qb[(y0 * HW + x0) * CQ + c];
                if (y0 >= 0 && y0 < HW && x0 + 1 >= 0 && x0 + 1 < HW)
                    img += w01 * qb[(y0 * HW + x0 + 1) * CQ + c];
                if (y0 + 1 >= 0 && y0 + 1 < HW && x0 >= 0 && x0 < HW)
                    img += w10 * qb[((y0 + 1) * HW + x0) * CQ + c];
                if (y0 + 1 >= 0 && y0 + 1 < HW && x0 + 1 >= 0 && x0 + 1 < HW)
                    img += w11 * qb[((y0 + 1) * HW + x0 + 1) * CQ + c];
            } else {
                int yy = y + dr, xx = x + dc;
                if (yy >= 0 && yy < HW && xx >= 0 && xx < HW)
                    img = qb[(yy * HW + xx) * CQ + c];
            }
            acc += e * img;
        }
    }
    out[(size_t)c * NPIX + p] = acc / ssum;
}

// ---- launcher --------------------------------------------------------------
extern "C" void kernel_launch(void* const* d_in, const int* in_sizes, int n_in,
                              void* d_out, int out_size, void* d_ws, size_t ws_size,
                              hipStream_t stream) {
    const float* fr = (const float*)d_in[0];   // (nref,1,64,48,48)
    const float* ft = (const float*)d_in[1];   // (1,64,48,48)
    const float* q  = (const float*)d_in[2];   // (nref,1,32,192,192)
    const void* refIdx = d_in[3];
    const void* curInd = d_in[4];
    int nref = in_sizes[0] / (CF * NPIX);

    float* ws  = (float*)d_ws;
    float* ftT = ws;
    float* qrT = ftT + (size_t)NPIX * CF;
    float* oY  = qrT + (size_t)nref * NPIX * CQ;
    float* oX  = oY + (size_t)nref * NPIX;
    float* vls = oX + (size_t)nref * NPIX;
    int* topi  = (int*)(vls + (size_t)nref * KTOP * NPIX);
    float* frMap = (float*)(topi + (size_t)nref * KTOP * NPIX);

    size_t base_fl = (size_t)NPIX * CF + (size_t)nref * NPIX * CQ +
                     2 * (size_t)nref * NPIX + 2 * (size_t)nref * KTOP * NPIX;
    size_t need_pad = (base_fl + (size_t)nref * PDIM * PDIM * CF) * sizeof(float);
    int padded = (ws_size >= need_pad) ? 1 : 0;

    int tmap = padded ? nref * PDIM * PDIM * CF : nref * NPIX * CF;
    int total = NPIX * CF + nref * NPIX * CQ + tmap;
    prep_kernel<<<(total + 255) / 256, 256, 0, stream>>>(fr, ft, q, nref,
                                                         ftT, qrT, frMap, padded);
    if (padded) {
        corr_topk_pad<<<dim3(NPIX / 4, nref), 256, 0, stream>>>(
            ftT, frMap, refIdx, curInd, oY, oX, vls, topi);
    } else {
        corr_topk_fb<<<dim3(NPIX / 4, nref), 256, 0, stream>>>(
            ftT, frMap, refIdx, curInd, oY, oX, vls, topi);
    }
    finalize_kernel<<<((NPIX * CQ) + 255) / 256, 256, 0, stream>>>(
        qrT, vls, topi, oY, oX, refIdx, curInd, nref, (float*)d_out);
}

// Round 5
// 183.409 us; speedup vs baseline: 1.2298x; 1.2298x over previous
//
#include <hip/hip_runtime.h>
#include <math.h>

#define HW 48
#define NPIX 2304          // 48*48
#define CF 64
#define CQ 32
#define RAD 12
#define PP 25
#define NTAP 625           // 25*25
#define KTOP 20
#define DILINT 16
#define QW 192
#define CSTRIDE 640        // corr row stride (625 padded)
#define NPB 6              // pixels per corr_band block
#define NC 30              // staged columns per row (j+dx: 0..29)
#define LROW 68            // LDS col stride in floats (bank-derotated)

// ---- helpers ---------------------------------------------------------------

// ref_index may arrive as int32 or int64; detect via first 8 bytes.
__device__ inline int read_ref_index(const void* rip, int r) {
    const long long* p64 = (const long long*)rip;
    long long v0 = p64[0];
    if (v0 >= 0 && v0 < 1000000) return (int)p64[r];   // plausible int64 layout
    return ((const int*)rip)[r];                       // int32 layout
}

__device__ inline int get_dil(const void* refIdx, const void* curInd, int r,
                              bool* isLong) {
    int cur = ((const int*)curInd)[0];
    int gap = cur - read_ref_index(refIdx, r);
    *isLong = gap > DILINT;
    return *isLong ? min(4, gap / DILINT + 1) : 1;
}

// ---- kernel 1: layout prep (compact frT, as round 3) -----------------------
__global__ void prep_kernel(const float* __restrict__ fr,
                            const float* __restrict__ ft,
                            const float* __restrict__ q, int nref,
                            float* __restrict__ ftT,
                            float* __restrict__ frT,
                            float* __restrict__ qrT) {
    int i = blockIdx.x * blockDim.x + threadIdx.x;
    int tft = NPIX * CF;
    int tfr = nref * NPIX * CF;
    int tqr = nref * NPIX * CQ;
    if (i < tft) {
        int p = i >> 6, c = i & 63;
        ftT[i] = ft[c * NPIX + p];
    } else if (i < tft + tfr) {
        int j = i - tft;
        int rr = j / (NPIX * CF);
        int rem = j % (NPIX * CF);
        int p = rem >> 6, c = rem & 63;
        frT[j] = fr[((size_t)rr * CF + c) * NPIX + p];
    } else if (i < tft + tfr + tqr) {
        int j = i - tft - tfr;
        int rr = j / (NPIX * CQ);
        int rem = j % (NPIX * CQ);
        int p = rem >> 5, c = rem & 31;
        int y = p / HW, x = p % HW;
        qrT[j] = q[(((size_t)rr * CQ + c) * QW + 4 * y) * QW + 4 * x];
    }
}

// ---- kernel 2a: integer-tap correlation, row-staged ------------------------
// Block = 6 pixels of one output row (stride dil), 256 threads.
// Per tap-row: stage 30 fr columns into LDS (coalesced, zero-padded),
// then lane t<150 owns tap (pixel j = t/25, dx = t%25) and computes its
// full 64-ch dot from LDS. corr[r][p][dy*25+dx] written directly.
__global__ __launch_bounds__(256) void corr_band(
    const float* __restrict__ ftT, const float* __restrict__ frT,
    const void* __restrict__ refIdx, const void* __restrict__ curInd,
    float* __restrict__ corr) {
    __shared__ float lrow[NC * LROW];   // 8160 B

    int tid = threadIdx.x;
    int bx = blockIdx.x % 9;
    int y = blockIdx.x / 9;
    int r = blockIdx.y;

    bool isLong;
    int dil = get_dil(refIdx, curInd, r, &isLong);
    int nb = (dil == 3) ? 9 : 8;        // blocks needed per row
    if (bx >= nb) return;

    int m = bx % dil, grp = bx / dil;
    int npr = HW / dil;                 // pixels per residue class

    int T = tid;
    bool active = T < NPB * PP;         // 150
    int j = active ? T / PP : 0;
    int dxi = active ? T - PP * j : 0;
    int xoff = grp * NPB + j;
    bool pvalid = active && (xoff < npr);
    int xj = m + dil * xoff;
    int pj = pvalid ? (y * HW + xj) : 0;
    int lc = j + dxi;                   // staged column 0..29

    // ft vector for this lane's pixel -> 16 float4 regs
    float4 fq[16];
    const float4* fp = (const float4*)(ftT + (size_t)pj * CF);
#pragma unroll
    for (int i = 0; i < 16; ++i) fq[i] = fp[i];

    const float* frb = frT + (size_t)r * NPIX * CF;
    float* outb = corr + ((size_t)r * NPIX + pj) * CSTRIDE + dxi;
    int gc0 = m + dil * (grp * NPB - RAD);   // global col for lc=0

    for (int dy = 0; dy < PP; ++dy) {
        int yy = y + dil * (dy - RAD);
        if (yy < 0 || yy >= HW) {            // block-uniform branch
            if (pvalid) outb[dy * PP] = 0.f;
            continue;
        }
        // stage 30 cols x 64 ch (480 16B-chunks over 256 threads)
        for (int k = tid; k < NC * 16; k += 256) {
            int col = k >> 4, sub = k & 15;
            int gc = gc0 + dil * col;
            float4 v = {0.f, 0.f, 0.f, 0.f};
            if (gc >= 0 && gc < HW)
                v = *(const float4*)(frb + ((size_t)yy * HW + gc) * CF + sub * 4);
            *(float4*)(lrow + col * LROW + sub * 4) = v;
        }
        __syncthreads();
        if (pvalid) {
            const float* bp = lrow + lc * LROW;
            float s = 0.f;
#pragma unroll
            for (int i = 0; i < 16; ++i) {
                float4 b = *(const float4*)(bp + 4 * i);
                s += fq[i].x * b.x + fq[i].y * b.y + fq[i].z * b.z + fq[i].w * b.w;
            }
            outb[dy * PP] = s;
        }
        __syncthreads();
    }
}

// ---- kernel 2b: softmax/offsets + bilinear corner pass + topK --------------
// Wave per (pixel, ref); creg loaded from the corr buffer.
__global__ __launch_bounds__(256) void corr_finish(
    const float* __restrict__ ftT, const float* __restrict__ frT,
    const float* __restrict__ corr,
    const void* __restrict__ refIdx, const void* __restrict__ curInd,
    float* __restrict__ offY, float* __restrict__ offX,
    float* __restrict__ vals, int* __restrict__ topi) {
    __shared__ float dg[4][680];

    int tid = threadIdx.x;
    int wid = tid >> 6, lane = tid & 63;
    int g = lane >> 4;
    int cs = lane & 15;
    int p = blockIdx.x * 4 + wid;
    int r = blockIdx.y;
    int y = p / HW, x = p % HW;

    bool isLong;
    int dil = get_dil(refIdx, curInd, r, &isLong);

    const float* cb = corr + ((size_t)r * NPIX + p) * CSTRIDE;
    float creg[10];
#pragma unroll
    for (int jj = 0; jj < 10; ++jj) {
        int t = lane + 64 * jj;
        creg[jj] = (t < NTAP) ? cb[t] : -INFINITY;
    }

    if (isLong) {
        // softmax over 625 taps -> expected offsets
        float M = -INFINITY;
#pragma unroll
        for (int jj = 0; jj < 10; ++jj) M = fmaxf(M, creg[jj]);
#pragma unroll
        for (int s = 32; s; s >>= 1) M = fmaxf(M, __shfl_xor(M, s, 64));
        float s0 = 0.f, sy = 0.f, sx = 0.f;
#pragma unroll
        for (int jj = 0; jj < 10; ++jj) {
            int t = lane + 64 * jj;
            if (t < NTAP) {
                float e = expf(creg[jj] - M);
                int dy = t / PP - RAD, dx = t % PP - RAD;
                s0 += e; sy += e * (float)dy; sx += e * (float)dx;
            }
        }
#pragma unroll
        for (int s = 32; s; s >>= 1) {
            s0 += __shfl_xor(s0, s, 64);
            sy += __shfl_xor(sy, s, 64);
            sx += __shfl_xor(sx, s, 64);
        }
        float oy = sy / s0 * (float)dil;
        float ox = sx / s0 * (float)dil;
        if (lane == 0) { offY[r * NPIX + p] = oy; offX[r * NPIX + p] = ox; }

        // 26x26 corner-dot grid, 16-lane cooperative dots (bounds-checked)
        float fy = (float)y + oy, fx = (float)x + ox;
        float fy0 = floorf(fy), fx0 = floorf(fx);
        float wy = fy - fy0, wx = fx - fx0;
        int iy0 = (int)fy0, ix0 = (int)fx0;
        float4 fqc = ((const float4*)(ftT + (size_t)p * CF))[cs];
        const float* frb = frT + (size_t)r * NPIX * CF;
        float* dgw = dg[wid];
        for (int rr = 0; rr < 169; ++rr) {
            int idx = 4 * rr + g;
            int a = idx / 26, bcol = idx % 26;
            int yy = iy0 - RAD + a, xx = ix0 - RAD + bcol;
            float s = 0.f;
            if (yy >= 0 && yy < HW && xx >= 0 && xx < HW) {
                float4 b = ((const float4*)(frb + (size_t)(yy * HW + xx) * CF))[cs];
                s = fqc.x * b.x + fqc.y * b.y + fqc.z * b.z + fqc.w * b.w;
            }
            s += __shfl_xor(s, 1, 64);
            s += __shfl_xor(s, 2, 64);
            s += __shfl_xor(s, 4, 64);
            s += __shfl_xor(s, 8, 64);
            if (cs == 0) dgw[idx] = s;
        }
        __builtin_amdgcn_wave_barrier();
        asm volatile("s_waitcnt lgkmcnt(0)" ::: "memory");
        __builtin_amdgcn_sched_barrier(0);

        float w00 = (1.f - wy) * (1.f - wx), w01 = (1.f - wy) * wx;
        float w10 = wy * (1.f - wx), w11 = wy * wx;
#pragma unroll
        for (int jj = 0; jj < 10; ++jj) {
            int t = lane + 64 * jj;
            if (t < NTAP) {
                int a = t / PP, bcol = t % PP;
                creg[jj] = w00 * dgw[a * 26 + bcol] + w01 * dgw[a * 26 + bcol + 1] +
                           w10 * dgw[(a + 1) * 26 + bcol] + w11 * dgw[(a + 1) * 26 + bcol + 1];
            }
        }
    }

    // top-K: 20 rounds of register argmax + shuffle butterfly; tie -> lowest t
    float* vout = vals + (size_t)r * KTOP * NPIX + p;
    int* iout = topi + (size_t)r * KTOP * NPIX + p;
    for (int k = 0; k < KTOP; ++k) {
        float bv = creg[0]; int bt = lane;
#pragma unroll
        for (int jj = 1; jj < 10; ++jj) {
            int t = lane + 64 * jj;
            if (creg[jj] > bv) { bv = creg[jj]; bt = t; }
        }
#pragma unroll
        for (int s = 32; s; s >>= 1) {
            float ov = __shfl_xor(bv, s, 64);
            int ot = __shfl_xor(bt, s, 64);
            if (ov > bv || (ov == bv && ot < bt)) { bv = ov; bt = ot; }
        }
        if (lane == 0) { vout[(size_t)k * NPIX] = bv; iout[(size_t)k * NPIX] = bt; }
        if ((bt & 63) == lane) {
            int jj2 = bt >> 6;
#pragma unroll
            for (int jj = 0; jj < 10; ++jj)
                if (jj == jj2) creg[jj] = -INFINITY;
        }
    }
}

// ---- kernel 3: softmax over 60 vals + gather colors + blend ---------------
__global__ __launch_bounds__(256) void finalize_kernel(
    const float* __restrict__ qrT, const float* __restrict__ vals,
    const int* __restrict__ topi, const float* __restrict__ offY,
    const float* __restrict__ offX, const void* __restrict__ refIdx,
    const void* __restrict__ curInd, int nref, float* __restrict__ out) {
    int tid = threadIdx.x;
    int p = blockIdx.x * 8 + (tid >> 5);
    int c = tid & 31;
    if (p >= NPIX) return;
    int y = p / HW, x = p % HW;
    int nk = nref * KTOP;

    float m = -INFINITY;
    for (int k = 0; k < nk; ++k) m = fmaxf(m, vals[(size_t)k * NPIX + p]);

    float ssum = 0.f, acc = 0.f;
    for (int rr = 0; rr < nref; ++rr) {
        bool isLong;
        get_dil(refIdx, curInd, rr, &isLong);
        float oy = 0.f, ox = 0.f;
        if (isLong) { oy = offY[rr * NPIX + p]; ox = offX[rr * NPIX + p]; }
        const float* qb = qrT + (size_t)rr * NPIX * CQ;
        for (int k = 0; k < KTOP; ++k) {
            int kk = rr * KTOP + k;
            float e = expf(vals[(size_t)kk * NPIX + p] - m);
            ssum += e;
            int id = topi[(size_t)kk * NPIX + p];
            int dr = id / PP - RAD, dc = id % PP - RAD;
            float img = 0.f;
            if (isLong) {
                float py = (float)y + oy + (float)dr;
                float px = (float)x + ox + (float)dc;
                float fy0 = floorf(py), fx0 = floorf(px);
                int y0 = (int)fy0, x0 = (int)fx0;
                float wy = py - fy0, wx = px - fx0;
                float w00 = (1.f - wy) * (1.f - wx), w01 = (1.f - wy) * wx;
                float w10 = wy * (1.f - wx), w11 = wy * wx;
                if (y0 >= 0 && y0 < HW && x0 >= 0 && x0 < HW)
                    img += w00 * qb[(y0 * HW + x0) * CQ + c];
                if (y0 >= 0 && y0 < HW && x0 + 1 >= 0 && x0 + 1 < HW)
                    img += w01 * qb[(y0 * HW + x0 + 1) * CQ + c];
                if (y0 + 1 >= 0 && y0 + 1 < HW && x0 >= 0 && x0 < HW)
                    img += w10 * qb[((y0 + 1) * HW + x0) * CQ + c];
                if (y0 + 1 >= 0 && y0 + 1 < HW && x0 + 1 >= 0 && x0 + 1 < HW)
                    img += w11 * qb[((y0 + 1) * HW + x0 + 1) * CQ + c];
            } else {
                int yy = y + dr, xx = x + dc;
                if (yy >= 0 && yy < HW && xx >= 0 && xx < HW)
                    img = qb[(yy * HW + xx) * CQ + c];
            }
            acc += e * img;
        }
    }
    out[(size_t)c * NPIX + p] = acc / ssum;
}

// ---- launcher --------------------------------------------------------------
extern "C" void kernel_launch(void* const* d_in, const int* in_sizes, int n_in,
                              void* d_out, int out_size, void* d_ws, size_t ws_size,
                              hipStream_t stream) {
    const float* fr = (const float*)d_in[0];   // (nref,1,64,48,48)
    const float* ft = (const float*)d_in[1];   // (1,64,48,48)
    const float* q  = (const float*)d_in[2];   // (nref,1,32,192,192)
    const void* refIdx = d_in[3];
    const void* curInd = d_in[4];
    int nref = in_sizes[0] / (CF * NPIX);

    float* ws  = (float*)d_ws;
    float* ftT = ws;
    float* frT = ftT + (size_t)NPIX * CF;
    float* qrT = frT + (size_t)nref * NPIX * CF;
    float* oY  = qrT + (size_t)nref * NPIX * CQ;
    float* oX  = oY + (size_t)nref * NPIX;
    float* vls = oX + (size_t)nref * NPIX;
    int* topi  = (int*)(vls + (size_t)nref * KTOP * NPIX);
    float* corr = (float*)(topi + (size_t)nref * KTOP * NPIX);

    int total = NPIX * CF + nref * NPIX * CF + nref * NPIX * CQ;
    prep_kernel<<<(total + 255) / 256, 256, 0, stream>>>(fr, ft, q, nref, ftT, frT, qrT);
    corr_band<<<dim3(HW * 9, nref), 256, 0, stream>>>(ftT, frT, refIdx, curInd, corr);
    corr_finish<<<dim3(NPIX / 4, nref), 256, 0, stream>>>(ftT, frT, corr, refIdx, curInd,
                                                          oY, oX, vls, topi);
    finalize_kernel<<<((NPIX * CQ) + 255) / 256, 256, 0, stream>>>(
        qrT, vls, topi, oY, oX, refIdx, curInd, nref, (float*)d_out);
}